// Round 2
// baseline (479.927 us; speedup 1.0000x reference)
//
#include <hip/hip_runtime.h>

// Problem constants (fixed by the reference):
//   x   [8,4096,256] f32  -> T=32768 tokens, D=256
//   W   [256,256]    f32  (z = x @ W^T + b)
//   b   [256]        f32  (zeros, still applied)
//   emb [1024,256]   f32  -> K=1024 codes
// Outputs concatenated in d_out (float32):
//   quant [T*256] | indices [T] (as float) | loss [1]
//
// Numerics note (indices must match the fp32 reference EXACTLY):
// reference dist = fl(fl(zz + ee[n]) - 2*dot_n), zz ~ 256 -> distances are
// quantized to ulp(256) ~ 3e-5; ~0.7% of tokens have exact fp32 ties which
// argmin resolves by FIRST index. We reproduce the same quantization
// (u = zz + ee[n]; s = fma(-2, dot, u); 2*dot is exact) and first-index
// tie-breaking. zz summation order is irrelevant: a k-ulp difference in zz
// shifts fl(zz+ee[n]) uniformly (exact lattice shift), preserving all
// comparisons.
#define TT   32768
#define DD   256
#define KK   1024
#define TM   128      // tokens per block (k_proj / k_vq)
#define BKC  32       // k-block depth
#define NC   128      // codes / outs per N-chunk
#define AS_S 132      // LDS row stride (floats), 16B-aligned (132*4=528=33*16)
#define BS_S 132

// ---------------------------------------------------------------------------
// Kernel 0: ee[n] = sum_d emb[n][d]^2
__global__ void k_ee(const float* __restrict__ emb, float* __restrict__ ee) {
    int n = blockIdx.x * 256 + threadIdx.x;
    if (n >= KK) return;
    const float4* r = (const float4*)(emb + (size_t)n * DD);
    float s = 0.f;
#pragma unroll
    for (int i = 0; i < DD / 4; ++i) {
        float4 v = r[i];
        s += v.x * v.x + v.y * v.y + v.z * v.z + v.w * v.w;
    }
    ee[n] = s;
}

// ---------------------------------------------------------------------------
// Kernel 1: z = x @ W^T + b, written row-major into the quant region of d_out.
__launch_bounds__(256, 1)
__global__ void k_proj(const float* __restrict__ x, const float* __restrict__ W,
                       const float* __restrict__ bias, float* __restrict__ z) {
    __shared__ float As[BKC][AS_S];
    __shared__ float Bs[BKC][BS_S];
    const int tid = threadIdx.x;
    const int tx = tid & 15;       // code/out group: 8 outs
    const int ty = tid >> 4;       // token group: 8 tokens
    const int t0 = blockIdx.x * TM;

    for (int nc = 0; nc < DD / NC; ++nc) {     // 2 chunks of 128 outputs
        const int nbase = nc * NC;
        float acc[8][8];
#pragma unroll
        for (int i = 0; i < 8; ++i)
#pragma unroll
            for (int j = 0; j < 8; ++j) acc[i][j] = 0.f;

        for (int kb = 0; kb < DD; kb += BKC) {
            __syncthreads();
            // stage A = x[t0..t0+127][kb..kb+31] transposed
#pragma unroll
            for (int j = 0; j < 4; ++j) {
                int idx = j * 256 + tid;           // 0..1023
                int row = idx >> 3;                // 0..127
                int c4  = idx & 7;                 // float4 within 32 cols
                float4 v = *(const float4*)(x + (size_t)(t0 + row) * DD + kb + c4 * 4);
                As[c4 * 4 + 0][row] = v.x;
                As[c4 * 4 + 1][row] = v.y;
                As[c4 * 4 + 2][row] = v.z;
                As[c4 * 4 + 3][row] = v.w;
            }
            // stage B = W[nbase..nbase+127][kb..kb+31] transposed
#pragma unroll
            for (int j = 0; j < 4; ++j) {
                int idx = j * 256 + tid;
                int row = idx >> 3;
                int c4  = idx & 7;
                float4 v = *(const float4*)(W + (size_t)(nbase + row) * DD + kb + c4 * 4);
                Bs[c4 * 4 + 0][row] = v.x;
                Bs[c4 * 4 + 1][row] = v.y;
                Bs[c4 * 4 + 2][row] = v.z;
                Bs[c4 * 4 + 3][row] = v.w;
            }
            __syncthreads();
#pragma unroll 8
            for (int kk = 0; kk < BKC; ++kk) {
                float4 a0 = *(const float4*)&As[kk][ty * 8];
                float4 a1 = *(const float4*)&As[kk][ty * 8 + 4];
                float4 b0 = *(const float4*)&Bs[kk][tx * 8];
                float4 b1 = *(const float4*)&Bs[kk][tx * 8 + 4];
                float av[8] = {a0.x, a0.y, a0.z, a0.w, a1.x, a1.y, a1.z, a1.w};
                float bv[8] = {b0.x, b0.y, b0.z, b0.w, b1.x, b1.y, b1.z, b1.w};
#pragma unroll
                for (int i = 0; i < 8; ++i)
#pragma unroll
                    for (int j = 0; j < 8; ++j)
                        acc[i][j] = fmaf(av[i], bv[j], acc[i][j]);
            }
        }
        // epilogue: z[t][n] = acc + bias[n]
        float bv[8];
#pragma unroll
        for (int j = 0; j < 8; ++j) bv[j] = bias[nbase + tx * 8 + j];
#pragma unroll
        for (int i = 0; i < 8; ++i) {
            int t = t0 + ty * 8 + i;
            float* dst = z + (size_t)t * DD + nbase + tx * 8;
            float4 o0 = {acc[i][0] + bv[0], acc[i][1] + bv[1], acc[i][2] + bv[2], acc[i][3] + bv[3]};
            float4 o1 = {acc[i][4] + bv[4], acc[i][5] + bv[5], acc[i][6] + bv[6], acc[i][7] + bv[7]};
            *(float4*)(dst)     = o0;
            *(float4*)(dst + 4) = o1;
        }
    }
}

// ---------------------------------------------------------------------------
// Kernel 2: distances + argmin + gather/quant + loss partials.
// zq points at the quant region of d_out, which currently holds z; after the
// argmin, each block overwrites its own rows with emb[idx].
__launch_bounds__(256, 1)
__global__ void k_vq(float* __restrict__ zq, const float* __restrict__ emb,
                     const float* __restrict__ ee, float* __restrict__ out_idx,
                     float* __restrict__ partial) {
    __shared__ float As[BKC][AS_S];
    __shared__ float Bs[BKC][BS_S];
    __shared__ float zzs[TM];
    __shared__ int   idxs[TM];
    __shared__ float red[4];
    const int tid = threadIdx.x;
    const int tx = tid & 15;
    const int ty = tid >> 4;
    const int t0 = blockIdx.x * TM;

    // --- zz[t] = sum_d z[t][d]^2 (order-insensitive; see numerics note) ---
    {
        const int tl   = tid >> 1;      // token 0..127
        const int part = tid & 1;       // half of the row
        const float* zrow = zq + (size_t)(t0 + tl) * DD + part * (DD / 2);
        float s = 0.f;
#pragma unroll
        for (int k = 0; k < DD / 8; ++k) {
            float4 v = *(const float4*)(zrow + k * 4);
            s += v.x * v.x + v.y * v.y + v.z * v.z + v.w * v.w;
        }
        s += __shfl_xor(s, 1);          // combine the two halves (same wave)
        if (part == 0) zzs[tl] = s;
    }
    // (no syncthreads needed yet: first use is after the first staging sync)

    float bestv[8];
    int   besti[8];
#pragma unroll
    for (int i = 0; i < 8; ++i) { bestv[i] = 3.4e38f; besti[i] = 0; }

    for (int nc = 0; nc < KK / NC; ++nc) {     // 8 chunks of 128 codes
        const int nbase = nc * NC;
        float acc[8][8];
#pragma unroll
        for (int i = 0; i < 8; ++i)
#pragma unroll
            for (int j = 0; j < 8; ++j) acc[i][j] = 0.f;

        for (int kb = 0; kb < DD; kb += BKC) {
            __syncthreads();
            // stage A = z[t0..t0+127][kb..kb+31] transposed
#pragma unroll
            for (int j = 0; j < 4; ++j) {
                int idx = j * 256 + tid;
                int row = idx >> 3;
                int c4  = idx & 7;
                float4 v = *(const float4*)(zq + (size_t)(t0 + row) * DD + kb + c4 * 4);
                As[c4 * 4 + 0][row] = v.x;
                As[c4 * 4 + 1][row] = v.y;
                As[c4 * 4 + 2][row] = v.z;
                As[c4 * 4 + 3][row] = v.w;
            }
            // stage B = emb[nbase..nbase+127][kb..kb+31] transposed
#pragma unroll
            for (int j = 0; j < 4; ++j) {
                int idx = j * 256 + tid;
                int row = idx >> 3;
                int c4  = idx & 7;
                float4 v = *(const float4*)(emb + (size_t)(nbase + row) * DD + kb + c4 * 4);
                Bs[c4 * 4 + 0][row] = v.x;
                Bs[c4 * 4 + 1][row] = v.y;
                Bs[c4 * 4 + 2][row] = v.z;
                Bs[c4 * 4 + 3][row] = v.w;
            }
            __syncthreads();
#pragma unroll 8
            for (int kk = 0; kk < BKC; ++kk) {
                float4 a0 = *(const float4*)&As[kk][ty * 8];
                float4 a1 = *(const float4*)&As[kk][ty * 8 + 4];
                float4 b0 = *(const float4*)&Bs[kk][tx * 8];
                float4 b1 = *(const float4*)&Bs[kk][tx * 8 + 4];
                float av[8] = {a0.x, a0.y, a0.z, a0.w, a1.x, a1.y, a1.z, a1.w};
                float bv[8] = {b0.x, b0.y, b0.z, b0.w, b1.x, b1.y, b1.z, b1.w};
#pragma unroll
                for (int i = 0; i < 8; ++i)
#pragma unroll
                    for (int j = 0; j < 8; ++j)
                        acc[i][j] = fmaf(av[i], bv[j], acc[i][j]);
            }
        }
        // fold chunk into running argmin, replicating reference quantization:
        //   u = fl(zz + ee[n]);  s = fl(u - 2*dot)   (2*dot exact, FMA = same)
#pragma unroll
        for (int j = 0; j < 8; ++j) {
            int n = nbase + tx * 8 + j;
            float en = ee[n];
#pragma unroll
            for (int i = 0; i < 8; ++i) {
                float u = zzs[ty * 8 + i] + en;     // fp32 add (not contracted)
                float s = fmaf(-2.f, acc[i][j], u); // fl(u - 2*dot)
                if (s < bestv[i]) { bestv[i] = s; besti[i] = n; }
            }
        }
    }

    // reduce across the 16 tx lanes sharing each token group (first-min ties)
#pragma unroll
    for (int off = 1; off < 16; off <<= 1) {
#pragma unroll
        for (int i = 0; i < 8; ++i) {
            float ov = __shfl_xor(bestv[i], off);
            int   oi = __shfl_xor(besti[i], off);
            if (ov < bestv[i] || (ov == bestv[i] && oi < besti[i])) {
                bestv[i] = ov; besti[i] = oi;
            }
        }
    }
    if (tx == 0) {
#pragma unroll
        for (int i = 0; i < 8; ++i) {
            int tl = ty * 8 + i;
            idxs[tl] = besti[i];
            out_idx[t0 + tl] = (float)besti[i];
        }
    }
    __syncthreads();

    // stage 3: gather emb[idx] -> quant (overwriting z in-place), loss partial
    const int tl   = tid >> 1;          // 0..127
    const int part = tid & 1;
    const int widx = idxs[tl];
    const float* erow = emb + (size_t)widx * DD;
    float* qrow = zq + (size_t)(t0 + tl) * DD;
    float lsum = 0.f;
#pragma unroll
    for (int k = 0; k < 32; ++k) {
        int f = part + 2 * k;           // float4 index 0..63
        float4 e  = *(const float4*)(erow + f * 4);
        float4 zv = *(const float4*)(qrow + f * 4);
        float dx = e.x - zv.x, dy = e.y - zv.y, dz = e.z - zv.z, dw = e.w - zv.w;
        lsum += dx * dx + dy * dy + dz * dz + dw * dw;
        *(float4*)(qrow + f * 4) = e;
    }
    // block reduce
#pragma unroll
    for (int off = 32; off; off >>= 1) lsum += __shfl_down(lsum, off);
    if ((tid & 63) == 0) red[tid >> 6] = lsum;
    __syncthreads();
    if (tid == 0) partial[blockIdx.x] = red[0] + red[1] + red[2] + red[3];
}

// ---------------------------------------------------------------------------
// Kernel 3: final loss = 1.25 * sum(partial) / (T*D)
__global__ void k_loss(const float* __restrict__ partial, float* __restrict__ out_loss) {
    __shared__ float red[4];
    int tid = threadIdx.x;               // 256 threads, 256 partials
    float s = partial[tid];
#pragma unroll
    for (int off = 32; off; off >>= 1) s += __shfl_down(s, off);
    if ((tid & 63) == 0) red[tid >> 6] = s;
    __syncthreads();
    if (tid == 0)
        out_loss[0] = (red[0] + red[1] + red[2] + red[3]) * (1.25f / 8388608.0f);
}

// ---------------------------------------------------------------------------
extern "C" void kernel_launch(void* const* d_in, const int* in_sizes, int n_in,
                              void* d_out, int out_size, void* d_ws, size_t ws_size,
                              hipStream_t stream) {
    const float* x   = (const float*)d_in[0];
    const float* W   = (const float*)d_in[1];
    const float* b   = (const float*)d_in[2];
    const float* emb = (const float*)d_in[3];

    float* out   = (float*)d_out;
    float* quant = out;                         // T*D floats (holds z, then quant)
    float* oidx  = out + (size_t)TT * DD;       // T floats
    float* oloss = oidx + TT;                   // 1 float

    float* ee      = (float*)d_ws;              // KK floats
    float* partial = ee + KK;                   // TT/TM floats

    k_ee  <<<KK / 256, 256, 0, stream>>>(emb, ee);
    k_proj<<<TT / TM,  256, 0, stream>>>(x, W, b, quant);
    k_vq  <<<TT / TM,  256, 0, stream>>>(quant, emb, ee, oidx, partial);
    k_loss<<<1,        256, 0, stream>>>(partial, oloss);
}